// Round 1
// baseline (3806.427 us; speedup 1.0000x reference)
//
#include <hip/hip_runtime.h>
#include <hip/hip_bf16.h>

// Problem: B=4, T=2048, E=1024, H=16, HS=64. fp32 everywhere.
// M = B*T = 8192 token rows.

#define TM 128
#define TN 128
#define TK 8

// ---------------------------------------------------------------------------
// LayerNorm: one block per row of 1024 floats. 256 threads * float4.
// ---------------------------------------------------------------------------
__global__ __launch_bounds__(256)
void ln_kernel(const float* __restrict__ x, const float* __restrict__ g,
               const float* __restrict__ bta, float* __restrict__ y) {
    __shared__ float red[8];
    const int row = blockIdx.x;
    const int t = threadIdx.x;
    const float4 xv = ((const float4*)(x + (size_t)row * 1024))[t];
    float s = xv.x + xv.y + xv.z + xv.w;
    float q = xv.x*xv.x + xv.y*xv.y + xv.z*xv.z + xv.w*xv.w;
#pragma unroll
    for (int off = 32; off; off >>= 1) {
        s += __shfl_down(s, off, 64);
        q += __shfl_down(q, off, 64);
    }
    const int wave = t >> 6;
    if ((t & 63) == 0) { red[wave*2] = s; red[wave*2+1] = q; }
    __syncthreads();
    const float s_tot = red[0] + red[2] + red[4] + red[6];
    const float q_tot = red[1] + red[3] + red[5] + red[7];
    const float mu = s_tot * (1.0f/1024.0f);
    const float var = q_tot * (1.0f/1024.0f) - mu*mu;
    const float rs = rsqrtf(var + 1e-5f);
    const float4 gv = ((const float4*)g)[t];
    const float4 bv = ((const float4*)bta)[t];
    float4 ov;
    ov.x = (xv.x - mu)*rs*gv.x + bv.x;
    ov.y = (xv.y - mu)*rs*gv.y + bv.y;
    ov.z = (xv.z - mu)*rs*gv.z + bv.z;
    ov.w = (xv.w - mu)*rs*gv.w + bv.w;
    ((float4*)(y + (size_t)row * 1024))[t] = ov;
}

// ---------------------------------------------------------------------------
// Repack Wq/Wk/Wv [H,E,HS] -> Wcat [E, 3*E], col = proj*1024 + h*64 + d
// ---------------------------------------------------------------------------
__global__ __launch_bounds__(256)
void repack_qkv(const float* __restrict__ Wq, const float* __restrict__ Wk,
                const float* __restrict__ Wv, float* __restrict__ Wcat) {
    const int idx = blockIdx.x * 256 + threadIdx.x;   // 1024*3072 total
    const int k = idx / 3072;
    const int c = idx - k * 3072;
    const int p = c >> 10;
    const int r = c & 1023;
    const int h = r >> 6;
    const int d = r & 63;
    const float* W = (p == 0) ? Wq : ((p == 1) ? Wk : Wv);
    Wcat[idx] = W[((size_t)h * 1024 + k) * 64 + d];
}

// ---------------------------------------------------------------------------
// SGEMM: C[M,N] = op(A[M,K] @ B[K,N] + bias + Res). 128x128x8, 8x8/thread.
// ---------------------------------------------------------------------------
template<bool RELU, bool HAS_BIAS, bool HAS_RES>
__global__ __launch_bounds__(256)
void sgemm_kernel(const float* __restrict__ A, int lda,
                  const float* __restrict__ B, int ldb,
                  float* __restrict__ C, int ldc,
                  const float* __restrict__ bias,
                  const float* __restrict__ Res, int ldres,
                  int M, int N, int K) {
    __shared__ float As[TK][TM];   // transposed: As[k][m]
    __shared__ float Bs[TK][TN];   // Bs[k][n]
    const int tid = threadIdx.x;
    const int bm = blockIdx.y * TM;
    const int bn = blockIdx.x * TN;
    const int tx = tid & 15;
    const int ty = tid >> 4;

    // global load mapping
    const int a_row = tid >> 1;          // 0..127
    const int a_col = (tid & 1) * 4;     // 0 or 4
    const int b_row = tid >> 5;          // 0..7
    const int b_col = (tid & 31) * 4;    // 0..124

    const float* Aptr = A + (size_t)(bm + a_row) * lda + a_col;
    const float* Bptr = B + (size_t)b_row * ldb + bn + b_col;

    float acc[8][8];
#pragma unroll
    for (int i = 0; i < 8; ++i)
#pragma unroll
        for (int j = 0; j < 8; ++j) acc[i][j] = 0.f;

    for (int k0 = 0; k0 < K; k0 += TK) {
        const float4 av = *(const float4*)Aptr;
        const float4 bv = *(const float4*)Bptr;
        As[a_col+0][a_row] = av.x;
        As[a_col+1][a_row] = av.y;
        As[a_col+2][a_row] = av.z;
        As[a_col+3][a_row] = av.w;
        *(float4*)&Bs[b_row][b_col] = bv;
        __syncthreads();
#pragma unroll
        for (int k = 0; k < TK; ++k) {
            float ar[8], br[8];
            *(float4*)&ar[0] = *(const float4*)&As[k][ty << 2];
            *(float4*)&ar[4] = *(const float4*)&As[k][(ty << 2) + 64];
            *(float4*)&br[0] = *(const float4*)&Bs[k][tx << 2];
            *(float4*)&br[4] = *(const float4*)&Bs[k][(tx << 2) + 64];
#pragma unroll
            for (int i = 0; i < 8; ++i)
#pragma unroll
                for (int j = 0; j < 8; ++j)
                    acc[i][j] = fmaf(ar[i], br[j], acc[i][j]);
        }
        __syncthreads();
        Aptr += TK;
        Bptr += (size_t)TK * ldb;
    }

    const float* biasp = HAS_BIAS ? (bias + bn) : nullptr;
#pragma unroll
    for (int ih = 0; ih < 2; ++ih) {
#pragma unroll
        for (int i = 0; i < 4; ++i) {
            const int r = bm + ih*64 + (ty << 2) + i;
            float* crow = C + (size_t)r * ldc + bn;
#pragma unroll
            for (int jh = 0; jh < 2; ++jh) {
                const int c0 = jh*64 + (tx << 2);
                float4 v;
                v.x = acc[ih*4+i][jh*4+0];
                v.y = acc[ih*4+i][jh*4+1];
                v.z = acc[ih*4+i][jh*4+2];
                v.w = acc[ih*4+i][jh*4+3];
                if (HAS_BIAS) {
                    v.x += biasp[c0+0]; v.y += biasp[c0+1];
                    v.z += biasp[c0+2]; v.w += biasp[c0+3];
                }
                if (HAS_RES) {
                    const float4 rv = *(const float4*)(Res + (size_t)r * ldres + bn + c0);
                    v.x += rv.x; v.y += rv.y; v.z += rv.z; v.w += rv.w;
                }
                if (RELU) {
                    v.x = fmaxf(v.x, 0.f); v.y = fmaxf(v.y, 0.f);
                    v.z = fmaxf(v.z, 0.f); v.w = fmaxf(v.w, 0.f);
                }
                *(float4*)(crow + c0) = v;
            }
        }
    }
}

// ---------------------------------------------------------------------------
// Flash-style attention, fp32. Block = 64 q-rows of one (b,h). 64-key tiles.
// qkv layout: [token][p*1024 + h*64 + d], token = b*T + t.
// out layout: [token][h*64 + d]  (concat heads)
// ---------------------------------------------------------------------------
__global__ __launch_bounds__(256, 2)
void attn_kernel(const float* __restrict__ qkv, float* __restrict__ out) {
    __shared__ float qs[64][65];   // [d][i], pre-scaled
    __shared__ float ks[64][65];   // [d][j]
    __shared__ float ps[64][65];   // [j][i]
    __shared__ float vs[64][64];   // [j][d]
    const int T = 2048;
    const int b = blockIdx.y >> 4;
    const int h = blockIdx.y & 15;
    const int q0 = blockIdx.x << 6;
    const int tid = threadIdx.x;
    const int tx = tid & 15, ty = tid >> 4;
    const int lr = tid >> 2;            // 0..63
    const int lc = (tid & 3) << 4;      // 0,16,32,48
    const float scale = 0.125f;         // 1/sqrt(64)

    const size_t base = (size_t)b * T * 3072 + h * 64;

    {   // load Q tile (scaled), transposed into qs[d][i]
        const float* qp = qkv + base + (size_t)(q0 + lr) * 3072 + lc;
#pragma unroll
        for (int i = 0; i < 4; ++i) {
            const float4 v = *(const float4*)(qp + i*4);
            qs[lc + i*4 + 0][lr] = v.x * scale;
            qs[lc + i*4 + 1][lr] = v.y * scale;
            qs[lc + i*4 + 2][lr] = v.z * scale;
            qs[lc + i*4 + 3][lr] = v.w * scale;
        }
    }

    float m_run[4], l_run[4], oacc[4][4];
#pragma unroll
    for (int i = 0; i < 4; ++i) {
        m_run[i] = -1e30f; l_run[i] = 0.f;
#pragma unroll
        for (int j = 0; j < 4; ++j) oacc[i][j] = 0.f;
    }

    for (int kt = 0; kt < T; kt += 64) {
        const float* kp = qkv + base + 1024 + (size_t)(kt + lr) * 3072 + lc;
        const float* vp = qkv + base + 2048 + (size_t)(kt + lr) * 3072 + lc;
#pragma unroll
        for (int i = 0; i < 4; ++i) {
            const float4 v = *(const float4*)(kp + i*4);
            ks[lc + i*4 + 0][lr] = v.x;
            ks[lc + i*4 + 1][lr] = v.y;
            ks[lc + i*4 + 2][lr] = v.z;
            ks[lc + i*4 + 3][lr] = v.w;
            const float4 w = *(const float4*)(vp + i*4);
            *(float4*)&vs[lr][lc + i*4] = w;
        }
        __syncthreads();

        // S = q @ k^T  (rows i = ty*4.., cols j = tx*4..)
        float sacc[4][4];
#pragma unroll
        for (int i = 0; i < 4; ++i)
#pragma unroll
            for (int j = 0; j < 4; ++j) sacc[i][j] = 0.f;
#pragma unroll 8
        for (int d = 0; d < 64; ++d) {
            const float4 aq = *(const float4*)&qs[d][ty << 2];
            const float4 bk = *(const float4*)&ks[d][tx << 2];
            const float aa[4] = {aq.x, aq.y, aq.z, aq.w};
            const float bb[4] = {bk.x, bk.y, bk.z, bk.w};
#pragma unroll
            for (int i = 0; i < 4; ++i)
#pragma unroll
                for (int j = 0; j < 4; ++j)
                    sacc[i][j] = fmaf(aa[i], bb[j], sacc[i][j]);
        }

        // online softmax stats per row (16 threads with same ty share a row)
#pragma unroll
        for (int i = 0; i < 4; ++i) {
            float mx = fmaxf(fmaxf(sacc[i][0], sacc[i][1]),
                             fmaxf(sacc[i][2], sacc[i][3]));
#pragma unroll
            for (int off = 1; off < 16; off <<= 1)
                mx = fmaxf(mx, __shfl_xor(mx, off, 64));
            const float mn = fmaxf(m_run[i], mx);
            const float alpha = __expf(m_run[i] - mn);
            m_run[i] = mn;
            float rsum = 0.f;
#pragma unroll
            for (int j = 0; j < 4; ++j) {
                const float p = __expf(sacc[i][j] - mn);
                sacc[i][j] = p;
                rsum += p;
            }
#pragma unroll
            for (int off = 1; off < 16; off <<= 1)
                rsum += __shfl_xor(rsum, off, 64);
            l_run[i] = l_run[i] * alpha + rsum;
#pragma unroll
            for (int j = 0; j < 4; ++j) oacc[i][j] *= alpha;
        }

        // P transposed into LDS: ps[j][i]
#pragma unroll
        for (int i = 0; i < 4; ++i)
#pragma unroll
            for (int j = 0; j < 4; ++j)
                ps[(tx << 2) + j][(ty << 2) + i] = sacc[i][j];
        __syncthreads();

        // O += P @ V   (rows i = ty*4.., dims d = tx*4..)
#pragma unroll 8
        for (int j = 0; j < 64; ++j) {
            const float4 ap = *(const float4*)&ps[j][ty << 2];
            const float4 bv = *(const float4*)&vs[j][tx << 2];
            const float aa[4] = {ap.x, ap.y, ap.z, ap.w};
            const float bb[4] = {bv.x, bv.y, bv.z, bv.w};
#pragma unroll
            for (int i = 0; i < 4; ++i)
#pragma unroll
                for (int jj = 0; jj < 4; ++jj)
                    oacc[i][jj] = fmaf(aa[i], bb[jj], oacc[i][jj]);
        }
        __syncthreads();
    }

#pragma unroll
    for (int i = 0; i < 4; ++i) {
        const float inv = 1.0f / l_run[i];
        float4 ov;
        ov.x = oacc[i][0] * inv;
        ov.y = oacc[i][1] * inv;
        ov.z = oacc[i][2] * inv;
        ov.w = oacc[i][3] * inv;
        const int trow = q0 + (ty << 2) + i;
        *(float4*)(out + (size_t)(b*T + trow) * 1024 + h*64 + (tx << 2)) = ov;
    }
}

// ---------------------------------------------------------------------------
extern "C" void kernel_launch(void* const* d_in, const int* in_sizes, int n_in,
                              void* d_out, int out_size, void* d_ws, size_t ws_size,
                              hipStream_t stream) {
    const float* x     = (const float*)d_in[0];
    const float* ln1_g = (const float*)d_in[1];
    const float* ln1_b = (const float*)d_in[2];
    const float* Wq    = (const float*)d_in[3];
    const float* Wk    = (const float*)d_in[4];
    const float* Wv    = (const float*)d_in[5];
    const float* Wo    = (const float*)d_in[6];
    const float* bo    = (const float*)d_in[7];
    const float* ln2_g = (const float*)d_in[8];
    const float* ln2_b = (const float*)d_in[9];
    const float* W1    = (const float*)d_in[10];
    const float* b1    = (const float*)d_in[11];
    const float* W2    = (const float*)d_in[12];
    const float* b2    = (const float*)d_in[13];
    float* out = (float*)d_out;

    const int M = 8192;           // B*T
    float* wcat = (float*)d_ws;                          // [1024][3072]
    float* qkv  = wcat + (size_t)1024 * 3072;            // [8192][3072]
    float* hbuf = qkv  + (size_t)8192 * 3072;            // [8192][1024]
    float* a1c  = hbuf + (size_t)8192 * 1024;            // [8192][2048] chunk

    // 1. repack QKV weights
    repack_qkv<<<dim3(1024*3072/256), dim3(256), 0, stream>>>(Wq, Wk, Wv, wcat);
    // 2. h = LN1(x)
    ln_kernel<<<dim3(8192), dim3(256), 0, stream>>>(x, ln1_g, ln1_b, hbuf);
    // 3. qkv = h @ Wcat
    sgemm_kernel<false,false,false><<<dim3(3072/TN, M/TM), dim3(256), 0, stream>>>(
        hbuf, 1024, wcat, 3072, qkv, 3072, nullptr, nullptr, 0, M, 3072, 1024);
    // 4. attention -> hbuf (o, concat heads)
    attn_kernel<<<dim3(32, 64), dim3(256), 0, stream>>>(qkv, hbuf);
    // 5. x2 = x + o @ Wo + bo  -> out
    sgemm_kernel<false,true,true><<<dim3(1024/TN, M/TM), dim3(256), 0, stream>>>(
        hbuf, 1024, Wo, 1024, out, 1024, bo, x, 1024, M, 1024, 1024);
    // 6. h2 = LN2(x2) -> hbuf
    ln_kernel<<<dim3(8192), dim3(256), 0, stream>>>(out, ln2_g, ln2_b, hbuf);
    // 7. FFN in two 2048-column chunks of the hidden dim
    //    chunk 0: a1c = relu(h2 @ W1[:, 0:2048] + b1[0:2048]); out += a1c @ W2[0:2048, :]
    sgemm_kernel<true,true,false><<<dim3(2048/TN, M/TM), dim3(256), 0, stream>>>(
        hbuf, 1024, W1, 4096, a1c, 2048, b1, nullptr, 0, M, 2048, 1024);
    sgemm_kernel<false,false,true><<<dim3(1024/TN, M/TM), dim3(256), 0, stream>>>(
        a1c, 2048, W2, 1024, out, 1024, nullptr, out, 1024, M, 1024, 2048);
    //    chunk 1
    sgemm_kernel<true,true,false><<<dim3(2048/TN, M/TM), dim3(256), 0, stream>>>(
        hbuf, 1024, W1 + 2048, 4096, a1c, 2048, b1 + 2048, nullptr, 0, M, 2048, 1024);
    sgemm_kernel<false,true,true><<<dim3(1024/TN, M/TM), dim3(256), 0, stream>>>(
        a1c, 2048, W2 + (size_t)2048*1024, 1024, out, 1024, b2, out, 1024, M, 1024, 2048);
}

// Round 2
// 717.986 us; speedup vs baseline: 5.3015x; 5.3015x over previous
//
#include <hip/hip_runtime.h>
#include <stdint.h>

// B=4, T=2048, E=1024, H=16, HS=64.  M = 8192 token rows. All I/O fp32;
// matmuls run bf16-input / fp32-accumulate on MFMA (16x16x32_bf16).

typedef __attribute__((ext_vector_type(8))) short s16x8;   // 8 bf16 (4 VGPR)
typedef __attribute__((ext_vector_type(4))) float f32x4;   // MFMA acc
typedef unsigned short u16;
typedef __attribute__((ext_vector_type(4))) unsigned short u16x4;

__device__ __forceinline__ u16 f2bf(float f) {   // RNE fp32 -> bf16
    uint32_t u = __float_as_uint(f);
    u += 0x7fffu + ((u >> 16) & 1u);
    return (u16)(u >> 16);
}

// ---------------------------------------------------------------------------
// LayerNorm fp32 -> bf16. One block per 1024-float row.
// ---------------------------------------------------------------------------
__global__ __launch_bounds__(256)
void ln_bf16(const float* __restrict__ x, const float* __restrict__ g,
             const float* __restrict__ bta, u16* __restrict__ y) {
    __shared__ float red[8];
    const int row = blockIdx.x;
    const int t = threadIdx.x;
    const float4 xv = ((const float4*)(x + (size_t)row * 1024))[t];
    float s = xv.x + xv.y + xv.z + xv.w;
    float q = xv.x*xv.x + xv.y*xv.y + xv.z*xv.z + xv.w*xv.w;
#pragma unroll
    for (int off = 32; off; off >>= 1) {
        s += __shfl_down(s, off, 64);
        q += __shfl_down(q, off, 64);
    }
    if ((t & 63) == 0) { red[(t>>6)*2] = s; red[(t>>6)*2+1] = q; }
    __syncthreads();
    const float st = red[0]+red[2]+red[4]+red[6];
    const float qt = red[1]+red[3]+red[5]+red[7];
    const float mu = st * (1.f/1024.f);
    const float rs = rsqrtf(qt*(1.f/1024.f) - mu*mu + 1e-5f);
    const float4 gv = ((const float4*)g)[t];
    const float4 bv = ((const float4*)bta)[t];
    u16x4 o;
    o.x = f2bf((xv.x-mu)*rs*gv.x + bv.x);
    o.y = f2bf((xv.y-mu)*rs*gv.y + bv.y);
    o.z = f2bf((xv.z-mu)*rs*gv.z + bv.z);
    o.w = f2bf((xv.w-mu)*rs*gv.w + bv.w);
    ((u16x4*)(y + (size_t)row*1024))[t] = o;
}

// ---------------------------------------------------------------------------
// Generic transpose: out[n][k] = bf16(in[k][n]); in is [K][N] fp32.
// grid = (K/64, N/64), 256 threads, 64x64 LDS tile.
// ---------------------------------------------------------------------------
__global__ __launch_bounds__(256)
void transpose_f32_bf16(const float* __restrict__ in, u16* __restrict__ out,
                        int K, int N) {
    __shared__ float tile[64][65];
    const int k0 = blockIdx.x * 64;
    const int n0 = blockIdx.y * 64;
    const int t = threadIdx.x;
    const int r = t >> 2;
    const int c = (t & 3) * 16;
    const float* ip = in + (size_t)(k0 + r) * N + n0 + c;
#pragma unroll
    for (int i = 0; i < 4; ++i) {
        const float4 v = *(const float4*)(ip + i*4);
        tile[r][c+i*4+0]=v.x; tile[r][c+i*4+1]=v.y;
        tile[r][c+i*4+2]=v.z; tile[r][c+i*4+3]=v.w;
    }
    __syncthreads();
    u16 tmp[16] __attribute__((aligned(16)));
#pragma unroll
    for (int i = 0; i < 16; ++i) tmp[i] = f2bf(tile[c+i][r]);
    u16* op = out + (size_t)(n0 + r) * K + k0 + c;
    *(s16x8*)op       = *(const s16x8*)&tmp[0];
    *(s16x8*)(op + 8) = *(const s16x8*)&tmp[8];
}

// ---------------------------------------------------------------------------
// Pack Wq/Wk/Wv [H=16][E=1024][HS=64] -> WcatT [3072 n][1024 k] bf16,
// n = p*1024 + h*64 + d.  grid = (16 ktiles, 48 p*h).
// ---------------------------------------------------------------------------
__global__ __launch_bounds__(256)
void pack_wcat(const float* __restrict__ Wq, const float* __restrict__ Wk,
               const float* __restrict__ Wv, u16* __restrict__ out) {
    __shared__ float tile[64][65];
    const int ph = blockIdx.y;
    const int p = ph >> 4, h = ph & 15;
    const float* W = (p == 0) ? Wq : (p == 1 ? Wk : Wv);
    const float* in = W + (size_t)h * 64 * 1024;     // [1024 k][64 d]
    const int k0 = blockIdx.x * 64;
    const int t = threadIdx.x;
    const int r = t >> 2;
    const int c = (t & 3) * 16;
    const float* ip = in + (size_t)(k0 + r) * 64 + c;
#pragma unroll
    for (int i = 0; i < 4; ++i) {
        const float4 v = *(const float4*)(ip + i*4);
        tile[r][c+i*4+0]=v.x; tile[r][c+i*4+1]=v.y;
        tile[r][c+i*4+2]=v.z; tile[r][c+i*4+3]=v.w;
    }
    __syncthreads();
    u16 tmp[16] __attribute__((aligned(16)));
#pragma unroll
    for (int i = 0; i < 16; ++i) tmp[i] = f2bf(tile[c+i][r]);
    u16* op = out + (size_t)(p*1024 + h*64 + r) * 1024 + k0 + c;
    *(s16x8*)op       = *(const s16x8*)&tmp[0];
    *(s16x8*)(op + 8) = *(const s16x8*)&tmp[8];
}

// ---------------------------------------------------------------------------
// bf16 MFMA GEMM: C[M,N] = op(A[M,K] @ Bt[N,K]^T + bias + Res)
// 128x128 tile, BK=64, 4 waves (2x2 of 64x64), 4x4 frags of 16x16x32.
// Reg-staged LDS with XOR swizzle (conflict-free frag reads).
// ---------------------------------------------------------------------------
template<bool RELU, bool HAS_BIAS, bool HAS_RES, bool OUT_BF16>
__global__ __launch_bounds__(256, 2)
void bgemm(const u16* __restrict__ A, int lda,
           const u16* __restrict__ Bt, int ldb,
           void* __restrict__ Cv, int ldc,
           const float* __restrict__ bias,
           const float* __restrict__ Res, int ldres, int K)
{
    __shared__ u16 Als[128*64];
    __shared__ u16 Bls[128*64];
    const int tid = threadIdx.x;
    const int wid = tid >> 6, lane = tid & 63;
    const int bm = blockIdx.y * 128, bn = blockIdx.x * 128;
    const int wr = (wid >> 1) * 64, wc = (wid & 1) * 64;
    const int srow = tid >> 3;            // 0..31 (row within 32-row chunk)
    const int sce  = (tid & 7) * 8;       // element col within BK=64
    const int fr = lane & 15, fq = lane >> 4;

    const f32x4 zero = {0.f, 0.f, 0.f, 0.f};
    f32x4 acc[4][4];
#pragma unroll
    for (int m = 0; m < 4; ++m)
#pragma unroll
        for (int n = 0; n < 4; ++n) acc[m][n] = zero;

    const u16* Ap = A  + (size_t)(bm + srow) * lda + sce;
    const u16* Bp = Bt + (size_t)(bn + srow) * ldb + sce;
    const size_t a32 = (size_t)32 * lda, b32 = (size_t)32 * ldb;

    // swizzled LDS byte offsets for staging writes
    int wb[4];
#pragma unroll
    for (int c2 = 0; c2 < 4; ++c2) {
        const int row = c2*32 + srow;
        wb[c2] = row*128 + (((tid & 7) * 16) ^ ((row & 7) << 4));
    }

    // prologue: load k0 = 0
    s16x8 ar[4], br[4];
#pragma unroll
    for (int c2 = 0; c2 < 4; ++c2) {
        ar[c2] = *(const s16x8*)(Ap + c2*a32);
        br[c2] = *(const s16x8*)(Bp + c2*b32);
    }

    for (int k0 = 0; k0 < K; k0 += 64) {
        __syncthreads();                    // previous tile reads done
#pragma unroll
        for (int c2 = 0; c2 < 4; ++c2) {
            *(s16x8*)((char*)Als + wb[c2]) = ar[c2];
            *(s16x8*)((char*)Bls + wb[c2]) = br[c2];
        }
        __syncthreads();
        if (k0 + 64 < K) {                  // prefetch next tile (hidden under MFMA)
#pragma unroll
            for (int c2 = 0; c2 < 4; ++c2) {
                ar[c2] = *(const s16x8*)(Ap + (k0 + 64) + c2*a32);
                br[c2] = *(const s16x8*)(Bp + (k0 + 64) + c2*b32);
            }
        }
#pragma unroll
        for (int kk = 0; kk < 2; ++kk) {
            s16x8 af[4], bf[4];
#pragma unroll
            for (int m = 0; m < 4; ++m) {
                const int r = wr + m*16 + fr;
                const int cb = (kk*64 + fq*16) ^ ((r & 7) << 4);
                af[m] = *(const s16x8*)((const char*)Als + r*128 + cb);
            }
#pragma unroll
            for (int n = 0; n < 4; ++n) {
                const int r = wc + n*16 + fr;
                const int cb = (kk*64 + fq*16) ^ ((r & 7) << 4);
                bf[n] = *(const s16x8*)((const char*)Bls + r*128 + cb);
            }
#pragma unroll
            for (int m = 0; m < 4; ++m)
#pragma unroll
                for (int n = 0; n < 4; ++n)
                    acc[m][n] = __builtin_amdgcn_mfma_f32_16x16x32_bf16(
                        af[m], bf[n], acc[m][n], 0, 0, 0);
        }
    }

    // epilogue: C/D frag mapping col = lane&15, row = (lane>>4)*4 + j
    float* Cf = (float*)Cv;
    u16*  Cb = (u16*)Cv;
#pragma unroll
    for (int n = 0; n < 4; ++n) {
        const int col = bn + wc + n*16 + fr;
        const float bval = HAS_BIAS ? bias[col] : 0.f;
#pragma unroll
        for (int m = 0; m < 4; ++m) {
#pragma unroll
            for (int j = 0; j < 4; ++j) {
                const int row = bm + wr + m*16 + fq*4 + j;
                float v = acc[m][n][j] + bval;
                if (HAS_RES) v += Res[(size_t)row * ldres + col];
                if (RELU)    v = fmaxf(v, 0.f);
                if (OUT_BF16) Cb[(size_t)row * ldc + col] = f2bf(v);
                else          Cf[(size_t)row * ldc + col] = v;
            }
        }
    }
}

// ---------------------------------------------------------------------------
// Flash attention, bf16 MFMA. Block = 64 q-rows of one (b,h); 4 waves,
// wave w owns q-rows 16w..16w+15. K/V tiles of 64 keys. Online softmax fp32.
// qkv: [token][p*1024 + h*64 + d] bf16.  out: [token][h*64+d] bf16.
// ---------------------------------------------------------------------------
__global__ __launch_bounds__(256)
void attn_bf16(const u16* __restrict__ qkv, u16* __restrict__ out) {
    __shared__ u16 Qs[64*72];
    __shared__ u16 Ks[64*72];
    __shared__ u16 Vt[64*72];   // V transposed: Vt[d][key]
    __shared__ u16 Ps[64*72];
    const int b = blockIdx.y >> 4, h = blockIdx.y & 15;
    const int q0 = blockIdx.x << 6;
    const int tid = threadIdx.x;
    const int wid = tid >> 6, lane = tid & 63;
    const int fr = lane & 15, fq = lane >> 4;
    const int srow = tid >> 2;            // 0..63 key/q row
    const int sce  = (tid & 3) * 16;      // element col 0,16,32,48
    const size_t tokbase = (size_t)b * 2048;

    // stage Q (wave-local: wave w stages its own rows 16w..16w+15)
    {
        const u16* qp = qkv + (tokbase + q0 + srow) * 3072 + h*64 + sce;
        *(s16x8*)&Qs[srow*72 + sce]     = *(const s16x8*)qp;
        *(s16x8*)&Qs[srow*72 + sce + 8] = *(const s16x8*)(qp + 8);
    }
    const s16x8 qf0 = *(const s16x8*)&Qs[(wid*16 + fr)*72 + fq*8];
    const s16x8 qf1 = *(const s16x8*)&Qs[(wid*16 + fr)*72 + 32 + fq*8];

    float m_run[4] = {-3e38f, -3e38f, -3e38f, -3e38f};
    float l_run[4] = {0.f, 0.f, 0.f, 0.f};
    const f32x4 zero = {0.f, 0.f, 0.f, 0.f};
    f32x4 oacc[4];
#pragma unroll
    for (int nd = 0; nd < 4; ++nd) oacc[nd] = zero;

    for (int kt = 0; kt < 2048; kt += 64) {
        const u16* kp = qkv + (tokbase + kt + srow)*3072 + 1024 + h*64 + sce;
        const s16x8 kv0 = *(const s16x8*)kp;
        const s16x8 kv1 = *(const s16x8*)(kp + 8);
        const s16x8 vv0 = *(const s16x8*)(kp + 1024);
        const s16x8 vv1 = *(const s16x8*)(kp + 1032);
        __syncthreads();                  // previous tile's reads complete
        *(s16x8*)&Ks[srow*72 + sce]     = kv0;
        *(s16x8*)&Ks[srow*72 + sce + 8] = kv1;
#pragma unroll
        for (int i = 0; i < 8; ++i) {
            Vt[(sce + i)*72 + srow]     = (u16)vv0[i];
            Vt[(sce + i + 8)*72 + srow] = (u16)vv1[i];
        }
        __syncthreads();

        // S = Q K^T for this wave's 16 rows x 64 keys
        f32x4 sv[4];
#pragma unroll
        for (int n = 0; n < 4; ++n) sv[n] = zero;
#pragma unroll
        for (int n = 0; n < 4; ++n) {
            const s16x8 kf0 = *(const s16x8*)&Ks[(n*16 + fr)*72 + fq*8];
            const s16x8 kf1 = *(const s16x8*)&Ks[(n*16 + fr)*72 + 32 + fq*8];
            sv[n] = __builtin_amdgcn_mfma_f32_16x16x32_bf16(qf0, kf0, sv[n], 0,0,0);
            sv[n] = __builtin_amdgcn_mfma_f32_16x16x32_bf16(qf1, kf1, sv[n], 0,0,0);
        }

        // online softmax per owned row j (16 lanes sharing fq hold the row)
#pragma unroll
        for (int j = 0; j < 4; ++j) {
            const float s0 = sv[0][j]*0.125f, s1 = sv[1][j]*0.125f;
            const float s2 = sv[2][j]*0.125f, s3 = sv[3][j]*0.125f;
            float mx = fmaxf(fmaxf(s0, s1), fmaxf(s2, s3));
#pragma unroll
            for (int off = 1; off < 16; off <<= 1)
                mx = fmaxf(mx, __shfl_xor(mx, off, 64));
            const float mn = fmaxf(m_run[j], mx);
            const float al = __expf(m_run[j] - mn);
            m_run[j] = mn;
            const float p0 = __expf(s0 - mn), p1 = __expf(s1 - mn);
            const float p2 = __expf(s2 - mn), p3 = __expf(s3 - mn);
            float rs = p0 + p1 + p2 + p3;
#pragma unroll
            for (int off = 1; off < 16; off <<= 1)
                rs += __shfl_xor(rs, off, 64);
            l_run[j] = l_run[j]*al + rs;
#pragma unroll
            for (int nd = 0; nd < 4; ++nd) oacc[nd][j] *= al;
            const int prow = (wid*16 + fq*4 + j)*72;
            Ps[prow + fr]      = f2bf(p0);
            Ps[prow + 16 + fr] = f2bf(p1);
            Ps[prow + 32 + fr] = f2bf(p2);
            Ps[prow + 48 + fr] = f2bf(p3);
        }

        // O += P V  (wave-local P; Vt shared)
        const s16x8 pf0 = *(const s16x8*)&Ps[(wid*16 + fr)*72 + fq*8];
        const s16x8 pf1 = *(const s16x8*)&Ps[(wid*16 + fr)*72 + 32 + fq*8];
#pragma unroll
        for (int nd = 0; nd < 4; ++nd) {
            const s16x8 vf0 = *(const s16x8*)&Vt[(nd*16 + fr)*72 + fq*8];
            const s16x8 vf1 = *(const s16x8*)&Vt[(nd*16 + fr)*72 + 32 + fq*8];
            oacc[nd] = __builtin_amdgcn_mfma_f32_16x16x32_bf16(pf0, vf0, oacc[nd], 0,0,0);
            oacc[nd] = __builtin_amdgcn_mfma_f32_16x16x32_bf16(pf1, vf1, oacc[nd], 0,0,0);
        }
    }

#pragma unroll
    for (int j = 0; j < 4; ++j) {
        const float inv = 1.0f / l_run[j];
        const size_t row = tokbase + q0 + wid*16 + fq*4 + j;
#pragma unroll
        for (int nd = 0; nd < 4; ++nd)
            out[row*1024 + h*64 + nd*16 + fr] = f2bf(oacc[nd][j] * inv);
    }
}

// ---------------------------------------------------------------------------
extern "C" void kernel_launch(void* const* d_in, const int* in_sizes, int n_in,
                              void* d_out, int out_size, void* d_ws, size_t ws_size,
                              hipStream_t stream) {
    (void)in_sizes; (void)n_in; (void)out_size; (void)ws_size;
    const float* x     = (const float*)d_in[0];
    const float* ln1_g = (const float*)d_in[1];
    const float* ln1_b = (const float*)d_in[2];
    const float* Wq    = (const float*)d_in[3];
    const float* Wk    = (const float*)d_in[4];
    const float* Wv    = (const float*)d_in[5];
    const float* Wo    = (const float*)d_in[6];
    const float* bo    = (const float*)d_in[7];
    const float* ln2_g = (const float*)d_in[8];
    const float* ln2_b = (const float*)d_in[9];
    const float* W1    = (const float*)d_in[10];
    const float* b1    = (const float*)d_in[11];
    const float* W2    = (const float*)d_in[12];
    const float* b2    = (const float*)d_in[13];
    float* out = (float*)d_out;

    char* w = (char*)d_ws;
    u16* WcatT = (u16*)w;  w += (size_t)3072*1024*2;   // [3072 n][1024 k]
    u16* WoT   = (u16*)w;  w += (size_t)1024*1024*2;   // [1024 n][1024 k]
    u16* W1T   = (u16*)w;  w += (size_t)4096*1024*2;   // [4096 n][1024 k]
    u16* W2T   = (u16*)w;  w += (size_t)1024*4096*2;   // [1024 n][4096 k]
    u16* hb    = (u16*)w;  w += (size_t)8192*1024*2;   // LN out (reused for LN2)
    u16* qkvb  = (u16*)w;  w += (size_t)8192*3072*2;   // qkv projections
    u16* attno = (u16*)w;  w += (size_t)8192*1024*2;   // attention out
    u16* a1    = (u16*)w;  w += (size_t)8192*4096*2;   // FFN hidden

    // weight packs (bf16, transposed to [N][K])
    pack_wcat<<<dim3(16, 48), 256, 0, stream>>>(Wq, Wk, Wv, WcatT);
    transpose_f32_bf16<<<dim3(16, 16), 256, 0, stream>>>(Wo, WoT, 1024, 1024);
    transpose_f32_bf16<<<dim3(16, 64), 256, 0, stream>>>(W1, W1T, 1024, 4096);
    transpose_f32_bf16<<<dim3(64, 16), 256, 0, stream>>>(W2, W2T, 4096, 1024);

    // h = LN1(x)
    ln_bf16<<<dim3(8192), 256, 0, stream>>>(x, ln1_g, ln1_b, hb);
    // qkv = h @ Wcat
    bgemm<false,false,false,true><<<dim3(24, 64), 256, 0, stream>>>(
        hb, 1024, WcatT, 1024, qkvb, 3072, nullptr, nullptr, 0, 1024);
    // attention
    attn_bf16<<<dim3(32, 64), 256, 0, stream>>>(qkvb, attno);
    // x2 = x + o @ Wo + bo   (fp32 out)
    bgemm<false,true,true,false><<<dim3(8, 64), 256, 0, stream>>>(
        attno, 1024, WoT, 1024, out, 1024, bo, x, 1024, 1024);
    // h2 = LN2(x2)
    ln_bf16<<<dim3(8192), 256, 0, stream>>>(out, ln2_g, ln2_b, hb);
    // a1 = relu(h2 @ W1 + b1)  (bf16 out)
    bgemm<true,true,false,true><<<dim3(32, 64), 256, 0, stream>>>(
        hb, 1024, W1T, 1024, a1, 4096, b1, nullptr, 0, 1024);
    // out = x2 + a1 @ W2 + b2  (fp32, in-place residual)
    bgemm<false,true,true,false><<<dim3(8, 64), 256, 0, stream>>>(
        a1, 4096, W2T, 4096, out, 1024, b2, out, 1024, 4096);
}

// Round 3
// 634.648 us; speedup vs baseline: 5.9977x; 1.1313x over previous
//
#include <hip/hip_runtime.h>
#include <stdint.h>

// B=4, T=2048, E=1024, H=16, HS=64.  M = 8192 token rows. All I/O fp32;
// matmuls run bf16-input / fp32-accumulate on MFMA (16x16x32_bf16).

typedef __attribute__((ext_vector_type(8))) short s16x8;   // 8 bf16 (4 VGPR)
typedef __attribute__((ext_vector_type(4))) float f32x4;   // MFMA acc
typedef unsigned short u16;
typedef __attribute__((ext_vector_type(4))) unsigned short u16x4;

// XOR swizzle: spreads row r's 16B blocks across banks; fixes both
// adjacent-row frag reads and rows-16-apart transpose writes.
#define XSW(r) ((((r) & 7) ^ (((r) >> 3) & 7)) << 4)

__device__ __forceinline__ u16 f2bf(float f) {   // RNE fp32 -> bf16
    uint32_t u = __float_as_uint(f);
    u += 0x7fffu + ((u >> 16) & 1u);
    return (u16)(u >> 16);
}
__device__ __forceinline__ float bf2f(u16 u) {
    return __uint_as_float(((uint32_t)u) << 16);
}
__device__ __forceinline__ uint32_t pk2(float a, float b) {
    return (uint32_t)f2bf(a) | ((uint32_t)f2bf(b) << 16);
}

// async global(16B/lane) -> LDS (wave-uniform base + lane*16)
__device__ __forceinline__ void gld16(const void* g, void* l) {
    __builtin_amdgcn_global_load_lds(
        (const __attribute__((address_space(1))) unsigned int*)g,
        (__attribute__((address_space(3))) unsigned int*)l, 16, 0, 0);
}

// ---------------------------------------------------------------------------
// LayerNorm fp32 -> bf16. One block per 1024-float row.
// ---------------------------------------------------------------------------
__global__ __launch_bounds__(256)
void ln_bf16(const float* __restrict__ x, const float* __restrict__ g,
             const float* __restrict__ bta, u16* __restrict__ y) {
    __shared__ float red[8];
    const int row = blockIdx.x;
    const int t = threadIdx.x;
    const float4 xv = ((const float4*)(x + (size_t)row * 1024))[t];
    float s = xv.x + xv.y + xv.z + xv.w;
    float q = xv.x*xv.x + xv.y*xv.y + xv.z*xv.z + xv.w*xv.w;
#pragma unroll
    for (int off = 32; off; off >>= 1) {
        s += __shfl_down(s, off, 64);
        q += __shfl_down(q, off, 64);
    }
    if ((t & 63) == 0) { red[(t>>6)*2] = s; red[(t>>6)*2+1] = q; }
    __syncthreads();
    const float st = red[0]+red[2]+red[4]+red[6];
    const float qt = red[1]+red[3]+red[5]+red[7];
    const float mu = st * (1.f/1024.f);
    const float rs = rsqrtf(qt*(1.f/1024.f) - mu*mu + 1e-5f);
    const float4 gv = ((const float4*)g)[t];
    const float4 bv = ((const float4*)bta)[t];
    u16x4 o;
    o.x = f2bf((xv.x-mu)*rs*gv.x + bv.x);
    o.y = f2bf((xv.y-mu)*rs*gv.y + bv.y);
    o.z = f2bf((xv.z-mu)*rs*gv.z + bv.z);
    o.w = f2bf((xv.w-mu)*rs*gv.w + bv.w);
    ((u16x4*)(y + (size_t)row*1024))[t] = o;
}

// ---------------------------------------------------------------------------
// Generic transpose: out[n][k] = bf16(in[k][n]); in is [K][N] fp32.
// ---------------------------------------------------------------------------
__global__ __launch_bounds__(256)
void transpose_f32_bf16(const float* __restrict__ in, u16* __restrict__ out,
                        int K, int N) {
    __shared__ float tile[64][65];
    const int k0 = blockIdx.x * 64;
    const int n0 = blockIdx.y * 64;
    const int t = threadIdx.x;
    const int r = t >> 2;
    const int c = (t & 3) * 16;
    const float* ip = in + (size_t)(k0 + r) * N + n0 + c;
#pragma unroll
    for (int i = 0; i < 4; ++i) {
        const float4 v = *(const float4*)(ip + i*4);
        tile[r][c+i*4+0]=v.x; tile[r][c+i*4+1]=v.y;
        tile[r][c+i*4+2]=v.z; tile[r][c+i*4+3]=v.w;
    }
    __syncthreads();
    u16 tmp[16] __attribute__((aligned(16)));
#pragma unroll
    for (int i = 0; i < 16; ++i) tmp[i] = f2bf(tile[c+i][r]);
    u16* op = out + (size_t)(n0 + r) * K + k0 + c;
    *(s16x8*)op       = *(const s16x8*)&tmp[0];
    *(s16x8*)(op + 8) = *(const s16x8*)&tmp[8];
}

// ---------------------------------------------------------------------------
// Pack Wq/Wk/Wv [H=16][E=1024][HS=64] -> WcatT [3072 n][1024 k] bf16.
// ---------------------------------------------------------------------------
__global__ __launch_bounds__(256)
void pack_wcat(const float* __restrict__ Wq, const float* __restrict__ Wk,
               const float* __restrict__ Wv, u16* __restrict__ out) {
    __shared__ float tile[64][65];
    const int ph = blockIdx.y;
    const int p = ph >> 4, h = ph & 15;
    const float* W = (p == 0) ? Wq : (p == 1 ? Wk : Wv);
    const float* in = W + (size_t)h * 64 * 1024;     // [1024 k][64 d]
    const int k0 = blockIdx.x * 64;
    const int t = threadIdx.x;
    const int r = t >> 2;
    const int c = (t & 3) * 16;
    const float* ip = in + (size_t)(k0 + r) * 64 + c;
#pragma unroll
    for (int i = 0; i < 4; ++i) {
        const float4 v = *(const float4*)(ip + i*4);
        tile[r][c+i*4+0]=v.x; tile[r][c+i*4+1]=v.y;
        tile[r][c+i*4+2]=v.z; tile[r][c+i*4+3]=v.w;
    }
    __syncthreads();
    u16 tmp[16] __attribute__((aligned(16)));
#pragma unroll
    for (int i = 0; i < 16; ++i) tmp[i] = f2bf(tile[c+i][r]);
    u16* op = out + (size_t)(p*1024 + h*64 + r) * 1024 + k0 + c;
    *(s16x8*)op       = *(const s16x8*)&tmp[0];
    *(s16x8*)(op + 8) = *(const s16x8*)&tmp[8];
}

// ---------------------------------------------------------------------------
// bf16 MFMA GEMM, m97 structure: 128x128 tile, BK=64, 4 waves, linear LDS,
// global_load_lds(16B) staging, 2-barrier K-loop.
// ---------------------------------------------------------------------------
template<bool RELU, bool HAS_BIAS, bool HAS_RES, bool OUT_BF16>
__global__ __launch_bounds__(256)
void bgemm(const u16* __restrict__ A, int lda,
           const u16* __restrict__ Bt, int ldb,
           void* Cv, int ldc,
           const float* __restrict__ bias,
           const float* Res, int ldres, int K)
{
    __shared__ u16 Als[128*64];
    __shared__ u16 Bls[128*64];
    const int tid = threadIdx.x;
    const int wid = tid >> 6, lane = tid & 63;
    const int bm = blockIdx.y * 128, bn = blockIdx.x * 128;
    const int wr = (wid >> 1) * 64, wc = (wid & 1) * 64;
    const int fr = lane & 15, fq = lane >> 4;
    const int sr8 = lane >> 3, sc8 = (lane & 7) * 8;

    const f32x4 zero = {0.f, 0.f, 0.f, 0.f};
    f32x4 acc[4][4];
#pragma unroll
    for (int m = 0; m < 4; ++m)
#pragma unroll
        for (int n = 0; n < 4; ++n) acc[m][n] = zero;

    // staging: issue q = wid*4+c covers rows 8q..8q+7; lane -> row 8q+(lane>>3),
    // u16 col (lane&7)*8. LDS dest = base(q) + lane*16B (linear row-major).
    const u16* Ap = A  + (size_t)(bm + wid*32 + sr8) * lda + sc8;
    const u16* Bp = Bt + (size_t)(bn + wid*32 + sr8) * ldb + sc8;
    u16* Alp = Als + wid*2048 + lane*8;
    u16* Blp = Bls + wid*2048 + lane*8;

    for (int k0 = 0; k0 < K; k0 += 64) {
#pragma unroll
        for (int c = 0; c < 4; ++c) {
            gld16(Ap + (size_t)(c*8)*lda + k0, Alp + c*512);
            gld16(Bp + (size_t)(c*8)*ldb + k0, Blp + c*512);
        }
        __syncthreads();   // drains vmcnt: tile resident
#pragma unroll
        for (int kk = 0; kk < 2; ++kk) {
            s16x8 af[4], bf[4];
#pragma unroll
            for (int m = 0; m < 4; ++m)
                af[m] = *(const s16x8*)((const char*)Als + (wr+m*16+fr)*128 + kk*64 + fq*16);
#pragma unroll
            for (int n = 0; n < 4; ++n)
                bf[n] = *(const s16x8*)((const char*)Bls + (wc+n*16+fr)*128 + kk*64 + fq*16);
#pragma unroll
            for (int m = 0; m < 4; ++m)
#pragma unroll
                for (int n = 0; n < 4; ++n)
                    acc[m][n] = __builtin_amdgcn_mfma_f32_16x16x32_bf16(
                        af[m], bf[n], acc[m][n], 0, 0, 0);
        }
        __syncthreads();   // reads done before next overwrite
    }

    // epilogue: C/D frag mapping col = lane&15, row = (lane>>4)*4 + j
    float* Cf = (float*)Cv;
    u16*  Cb = (u16*)Cv;
#pragma unroll
    for (int n = 0; n < 4; ++n) {
        const int col = bn + wc + n*16 + fr;
        const float bval = HAS_BIAS ? bias[col] : 0.f;
#pragma unroll
        for (int m = 0; m < 4; ++m) {
#pragma unroll
            for (int j = 0; j < 4; ++j) {
                const int row = bm + wr + m*16 + fq*4 + j;
                float v = acc[m][n][j] + bval;
                if (HAS_RES) v += Res[(size_t)row * ldres + col];
                if (RELU)    v = fmaxf(v, 0.f);
                if (OUT_BF16) Cb[(size_t)row * ldc + col] = f2bf(v);
                else          Cf[(size_t)row * ldc + col] = v;
            }
        }
    }
}

// ---------------------------------------------------------------------------
// Flash attention, swapped-QK^T bf16 MFMA.
// Block = 64 q-rows of one (b,h); 4 waves; wave owns 16 q-rows (q_local=fr).
// KVBLK=128. S^T = mfma(K,Q): lane holds 32 scores of its q-row -> softmax is
// in-register + 2 shfl_xor. O^T = mfma(V^T, P^T); P via wave-local swizzled
// LDS (no block barrier). All tiles XOR-swizzled (XSW) -> conflict-light.
// ---------------------------------------------------------------------------
__global__ __launch_bounds__(256)
void attn_bf16(const u16* __restrict__ qkv, u16* __restrict__ out) {
    __shared__ u16 Ks[128*64];      // [key][d]   stride 128B, XSW(key)
    __shared__ u16 Vt[64*128];      // [d][key]   stride 256B, XSW(d)
    __shared__ u16 Ps[4][16*128];   // per-wave [q16][key128] stride 256B, XSW(q)
    const int b = blockIdx.y >> 4, h = blockIdx.y & 15;
    const int q0 = blockIdx.x << 6;
    const int tid = threadIdx.x;
    const int wid = tid >> 6, lane = tid & 63;
    const int fr = lane & 15, fq = lane >> 4;
    const int srow = tid >> 2;           // 0..63
    const int sce  = (tid & 3) * 16;     // u16 col group
    const size_t tokbase = (size_t)b * 2048;
    const f32x4 zero = {0.f, 0.f, 0.f, 0.f};

    // ---- stage Q into Ps space (transient), build pre-scaled Q frags ----
    u16* Qst = (u16*)Ps;                 // [64 q][64 d], stride 128B, XSW(q)
    {
        const u16* qp = qkv + (tokbase + q0 + srow)*3072 + h*64 + sce;
        const s16x8 v0 = *(const s16x8*)qp;
        const s16x8 v1 = *(const s16x8*)(qp + 8);
        *(s16x8*)((char*)Qst + srow*128 + ((sce*2)      ^ XSW(srow))) = v0;
        *(s16x8*)((char*)Qst + srow*128 + ((sce*2 + 16) ^ XSW(srow))) = v1;
    }
    __syncthreads();
    s16x8 qf[2];     // B-operand frags: Q[q=fr][d=kk*32+fq*8+i], scaled 1/8
    {
        const int qrow = wid*16 + fr;
#pragma unroll
        for (int kk = 0; kk < 2; ++kk) {
            const s16x8 raw = *(const s16x8*)((const char*)Qst + qrow*128
                                 + ((kk*64 + fq*16) ^ XSW(qrow)));
#pragma unroll
            for (int i = 0; i < 8; ++i)
                qf[kk][i] = (short)f2bf(bf2f((u16)raw[i]) * 0.125f);
        }
    }

    float m_run = -1e30f, l_run = 0.f;
    f32x4 oacc[4];   // O^T frag nd: col q=fr, row d = nd*16+fq*4+j
#pragma unroll
    for (int nd = 0; nd < 4; ++nd) oacc[nd] = zero;

    for (int kt = 0; kt < 2048; kt += 128) {
        // global loads (K,V rows kt+srow and kt+64+srow), issued pre-barrier
        const u16* kp0 = qkv + (tokbase + kt + srow)*3072 + 1024 + h*64 + sce;
        const u16* kp1 = kp0 + (size_t)64*3072;
        const s16x8 ka0 = *(const s16x8*)kp0;
        const s16x8 ka1 = *(const s16x8*)(kp0 + 8);
        const s16x8 kb0 = *(const s16x8*)kp1;
        const s16x8 kb1 = *(const s16x8*)(kp1 + 8);
        const s16x8 va0 = *(const s16x8*)(kp0 + 1024);
        const s16x8 va1 = *(const s16x8*)(kp0 + 1032);
        const s16x8 vb0 = *(const s16x8*)(kp1 + 1024);
        const s16x8 vb1 = *(const s16x8*)(kp1 + 1032);
        __syncthreads();                 // (A) prev-tile reads done
        {   // K staging (b128, swizzled)
            const int r0 = srow, r1 = srow + 64;
            *(s16x8*)((char*)Ks + r0*128 + ((sce*2)      ^ XSW(r0))) = ka0;
            *(s16x8*)((char*)Ks + r0*128 + ((sce*2 + 16) ^ XSW(r0))) = ka1;
            *(s16x8*)((char*)Ks + r1*128 + ((sce*2)      ^ XSW(r1))) = kb0;
            *(s16x8*)((char*)Ks + r1*128 + ((sce*2 + 16) ^ XSW(r1))) = kb1;
        }
#pragma unroll
        for (int i = 0; i < 8; ++i) {    // V^T staging (b16, swizzled)
            const int d0 = sce + i, d1 = sce + 8 + i;
            *(u16*)((char*)Vt + d0*256 + ((srow*2)        ^ XSW(d0))) = (u16)va0[i];
            *(u16*)((char*)Vt + d1*256 + ((srow*2)        ^ XSW(d1))) = (u16)va1[i];
            *(u16*)((char*)Vt + d0*256 + (((srow+64)*2)   ^ XSW(d0))) = (u16)vb0[i];
            *(u16*)((char*)Vt + d1*256 + (((srow+64)*2)   ^ XSW(d1))) = (u16)vb1[i];
        }
        __syncthreads();                 // (B) tile resident

        // ---- S^T = mfma(K, Q): lane gets scores for q=fr, keys n*16+fq*4+j
        f32x4 sv[8];
#pragma unroll
        for (int n = 0; n < 8; ++n) {
            sv[n] = zero;
            const int r = n*16 + fr;
#pragma unroll
            for (int kk = 0; kk < 2; ++kk) {
                const s16x8 kf = *(const s16x8*)((const char*)Ks + r*128
                                     + ((kk*64 + fq*16) ^ XSW(r)));
                sv[n] = __builtin_amdgcn_mfma_f32_16x16x32_bf16(kf, qf[kk], sv[n], 0,0,0);
            }
        }

        // ---- online softmax: in-register over 32 values + 2 shfl_xor
        float pv[32];
        float mx = -1e30f;
#pragma unroll
        for (int n = 0; n < 8; ++n)
#pragma unroll
            for (int j = 0; j < 4; ++j) {
                const float s = sv[n][j];
                pv[n*4 + j] = s;
                mx = fmaxf(mx, s);
            }
        mx = fmaxf(mx, __shfl_xor(mx, 16, 64));
        mx = fmaxf(mx, __shfl_xor(mx, 32, 64));
        const float mn = fmaxf(m_run, mx);
        const float al = __expf(m_run - mn);
        m_run = mn;
        float rs = 0.f;
#pragma unroll
        for (int t = 0; t < 32; ++t) { pv[t] = __expf(pv[t] - mn); rs += pv[t]; }
        rs += __shfl_xor(rs, 16, 64);
        rs += __shfl_xor(rs, 32, 64);
        l_run = l_run * al + rs;
#pragma unroll
        for (int nd = 0; nd < 4; ++nd)
#pragma unroll
            for (int j = 0; j < 4; ++j) oacc[nd][j] *= al;

        // ---- P to wave-local LDS (packed b64, swizzled); no block barrier
        u16* Pw = (u16*)Ps + wid*2048;
#pragma unroll
        for (int n = 0; n < 8; ++n) {
            const uint64_t w = (uint64_t)pk2(pv[n*4+0], pv[n*4+1])
                             | ((uint64_t)pk2(pv[n*4+2], pv[n*4+3]) << 32);
            *(uint64_t*)((char*)Pw + fr*256 + ((n*32 + fq*8) ^ XSW(fr))) = w;
        }
        asm volatile("s_waitcnt lgkmcnt(0)" ::: "memory");
        __builtin_amdgcn_sched_barrier(0);

        // ---- O^T += mfma(V^T, P^T)
        s16x8 pf[4];
#pragma unroll
        for (int k2 = 0; k2 < 4; ++k2)
            pf[k2] = *(const s16x8*)((const char*)Pw + fr*256
                         + ((k2*64 + fq*16) ^ XSW(fr)));
#pragma unroll
        for (int nd = 0; nd < 4; ++nd) {
            const int d = nd*16 + fr;
#pragma unroll
            for (int k2 = 0; k2 < 4; ++k2) {
                const s16x8 vf = *(const s16x8*)((const char*)Vt + d*256
                                     + ((k2*64 + fq*16) ^ XSW(d)));
                oacc[nd] = __builtin_amdgcn_mfma_f32_16x16x32_bf16(vf, pf[k2], oacc[nd], 0,0,0);
            }
        }
    }

    // ---- epilogue: lane holds O[q=fr][d = nd*16+fq*4+j]
    const float inv = 1.0f / l_run;
    const size_t row = tokbase + q0 + wid*16 + fr;
#pragma unroll
    for (int nd = 0; nd < 4; ++nd) {
        u16x4 o;
#pragma unroll
        for (int j = 0; j < 4; ++j) o[j] = f2bf(oacc[nd][j] * inv);
        *(u16x4*)(out + row*1024 + h*64 + nd*16 + fq*4) = o;
    }
}

// ---------------------------------------------------------------------------
extern "C" void kernel_launch(void* const* d_in, const int* in_sizes, int n_in,
                              void* d_out, int out_size, void* d_ws, size_t ws_size,
                              hipStream_t stream) {
    (void)in_sizes; (void)n_in; (void)out_size; (void)ws_size;
    const float* x     = (const float*)d_in[0];
    const float* ln1_g = (const float*)d_in[1];
    const float* ln1_b = (const float*)d_in[2];
    const float* Wq    = (const float*)d_in[3];
    const float* Wk    = (const float*)d_in[4];
    const float* Wv    = (const float*)d_in[5];
    const float* Wo    = (const float*)d_in[6];
    const float* bo    = (const float*)d_in[7];
    const float* ln2_g = (const float*)d_in[8];
    const float* ln2_b = (const float*)d_in[9];
    const float* W1    = (const float*)d_in[10];
    const float* b1    = (const float*)d_in[11];
    const float* W2    = (const float*)d_in[12];
    const float* b2    = (const float*)d_in[13];
    float* out = (float*)d_out;

    char* w = (char*)d_ws;
    u16* WcatT = (u16*)w;  w += (size_t)3072*1024*2;   // [3072 n][1024 k]
    u16* WoT   = (u16*)w;  w += (size_t)1024*1024*2;   // [1024 n][1024 k]
    u16* W1T   = (u16*)w;  w += (size_t)4096*1024*2;   // [4096 n][1024 k]
    u16* W2T   = (u16*)w;  w += (size_t)1024*4096*2;   // [1024 n][4096 k]
    u16* hb    = (u16*)w;  w += (size_t)8192*1024*2;   // LN out (reused)
    u16* qkvb  = (u16*)w;  w += (size_t)8192*3072*2;   // qkv projections
    u16* attno = (u16*)w;  w += (size_t)8192*1024*2;   // attention out
    u16* a1    = (u16*)w;  w += (size_t)8192*4096*2;   // FFN hidden

    // weight packs (bf16, transposed to [N][K])
    pack_wcat<<<dim3(16, 48), 256, 0, stream>>>(Wq, Wk, Wv, WcatT);
    transpose_f32_bf16<<<dim3(16, 16), 256, 0, stream>>>(Wo, WoT, 1024, 1024);
    transpose_f32_bf16<<<dim3(16, 64), 256, 0, stream>>>(W1, W1T, 1024, 4096);
    transpose_f32_bf16<<<dim3(64, 16), 256, 0, stream>>>(W2, W2T, 4096, 1024);

    // h = LN1(x)
    ln_bf16<<<dim3(8192), 256, 0, stream>>>(x, ln1_g, ln1_b, hb);
    // qkv = h @ Wcat
    bgemm<false,false,false,true><<<dim3(24, 64), 256, 0, stream>>>(
        hb, 1024, WcatT, 1024, qkvb, 3072, nullptr, nullptr, 0, 1024);
    // attention
    attn_bf16<<<dim3(32, 64), 256, 0, stream>>>(qkvb, attno);
    // x2 = x + o @ Wo + bo   (fp32 out)
    bgemm<false,true,true,false><<<dim3(8, 64), 256, 0, stream>>>(
        attno, 1024, WoT, 1024, out, 1024, bo, x, 1024, 1024);
    // h2 = LN2(x2)
    ln_bf16<<<dim3(8192), 256, 0, stream>>>(out, ln2_g, ln2_b, hb);
    // a1 = relu(h2 @ W1 + b1)  (bf16 out)
    bgemm<true,true,false,true><<<dim3(32, 64), 256, 0, stream>>>(
        hb, 1024, W1T, 1024, a1, 4096, b1, nullptr, 0, 1024);
    // out = x2 + a1 @ W2 + b2  (fp32, in-place residual)
    bgemm<false,true,true,false><<<dim3(8, 64), 256, 0, stream>>>(
        a1, 4096, W2T, 4096, out, 1024, b2, out, 1024, 4096);
}